// Round 1
// baseline (153.805 us; speedup 1.0000x reference)
//
#include <hip/hip_runtime.h>
#include <hip/hip_bf16.h>

// CrossAttentionOutLayer: out[b,i,j] = (1/H) * sum_c Q'[b,i,c] * K[b,j,c]
//   Q' = SCALE*(rna@Wq.T + bq) + rel_bias   (c = h*DK+d == flat rel_bias idx)
//   K  = prot@Wk.T + bk
// B=8 N=1024 M=1024 DIM2=1280 KIN=1344 H=8 DK=64 HDK=512 SCALE=0.125

typedef __bf16 bf16x8 __attribute__((ext_vector_type(8)));
typedef float f32x4 __attribute__((ext_vector_type(4)));

constexpr int BK = 64;      // K-step (bf16 elements)
constexpr int LDSW = 72;    // padded LDS row stride (+8 bf16 = 16B -> kills bank conflicts)

// ---------------------------------------------------------------------------
// Projection: out[row, c] = f( sum_k A[row,k]*W[c,k] + bias[c] )
//   QT=1: f(v) = 0.125*(v) + rb[c]   (bias folded before scale)
//   QT=0: f(v) = v
// A: [8192, K] f32 row-major; W: [512, K] f32 row-major; out: [8192, 512] bf16
// grid: (512/128, 8192/128) = (4, 64); block 256 (4 waves, 2x2 of 64x64)
// ---------------------------------------------------------------------------
template<int QT>
__global__ __launch_bounds__(256, 2)
void proj_kernel(const float* __restrict__ A,
                 const float* __restrict__ W,
                 const float* __restrict__ bias,
                 const float* __restrict__ rb,
                 __bf16* __restrict__ out,
                 const int K)
{
    __shared__ __bf16 As[128 * LDSW];
    __shared__ __bf16 Bs[128 * LDSW];

    const int tid  = threadIdx.x;
    const int lane = tid & 63;
    const int wid  = tid >> 6;
    const int wr   = wid >> 1;       // wave row (0..1)
    const int wc   = wid & 1;        // wave col (0..1)
    const int brow = blockIdx.y * 128;
    const int bcol = blockIdx.x * 128;

    f32x4 acc[4][4] = {};

    // staging: 2 threads per row, 32 f32 each -> convert to bf16
    const int srow = tid >> 1;
    const int soff = (tid & 1) * 32;
    const float* aSrc = A + (size_t)(brow + srow) * K + soff;
    const float* bSrc = W + (size_t)(bcol + srow) * K + soff;
    __bf16* aDst = &As[srow * LDSW + soff];
    __bf16* bDst = &Bs[srow * LDSW + soff];

    const int fr = lane & 15;        // fragment row/col
    const int fk = (lane >> 4) * 8;  // fragment k offset

    for (int k0 = 0; k0 < K; k0 += BK) {
        __syncthreads();
        #pragma unroll
        for (int i = 0; i < 4; ++i) {
            f32x4 v0 = *(const f32x4*)(aSrc + k0 + i * 8);
            f32x4 v1 = *(const f32x4*)(aSrc + k0 + i * 8 + 4);
            bf16x8 p;
            p[0] = (__bf16)v0[0]; p[1] = (__bf16)v0[1];
            p[2] = (__bf16)v0[2]; p[3] = (__bf16)v0[3];
            p[4] = (__bf16)v1[0]; p[5] = (__bf16)v1[1];
            p[6] = (__bf16)v1[2]; p[7] = (__bf16)v1[3];
            *(bf16x8*)(aDst + i * 8) = p;
        }
        #pragma unroll
        for (int i = 0; i < 4; ++i) {
            f32x4 v0 = *(const f32x4*)(bSrc + k0 + i * 8);
            f32x4 v1 = *(const f32x4*)(bSrc + k0 + i * 8 + 4);
            bf16x8 p;
            p[0] = (__bf16)v0[0]; p[1] = (__bf16)v0[1];
            p[2] = (__bf16)v0[2]; p[3] = (__bf16)v0[3];
            p[4] = (__bf16)v1[0]; p[5] = (__bf16)v1[1];
            p[6] = (__bf16)v1[2]; p[7] = (__bf16)v1[3];
            *(bf16x8*)(bDst + i * 8) = p;
        }
        __syncthreads();

        #pragma unroll
        for (int kk = 0; kk < 2; ++kk) {
            bf16x8 af[4], bf[4];
            #pragma unroll
            for (int m = 0; m < 4; ++m)
                af[m] = *(const bf16x8*)(&As[(wr * 64 + m * 16 + fr) * LDSW + kk * 32 + fk]);
            #pragma unroll
            for (int n = 0; n < 4; ++n)
                bf[n] = *(const bf16x8*)(&Bs[(wc * 64 + n * 16 + fr) * LDSW + kk * 32 + fk]);
            #pragma unroll
            for (int m = 0; m < 4; ++m)
                #pragma unroll
                for (int n = 0; n < 4; ++n)
                    acc[m][n] = __builtin_amdgcn_mfma_f32_16x16x32_bf16(af[m], bf[n], acc[m][n], 0, 0, 0);
        }
    }

    // epilogue: C/D layout col = lane&15, row = (lane>>4)*4 + j  [m89-verified]
    const int r0 = (lane >> 4) * 4;
    #pragma unroll
    for (int n = 0; n < 4; ++n) {
        const int c = bcol + wc * 64 + n * 16 + fr;
        const float bv = bias[c];
        const float rv = QT ? rb[c] : 0.0f;
        #pragma unroll
        for (int m = 0; m < 4; ++m) {
            const int row = brow + wr * 64 + m * 16 + r0;
            #pragma unroll
            for (int j = 0; j < 4; ++j) {
                float v = acc[m][n][j] + bv;
                if (QT) v = 0.125f * v + rv;
                out[(size_t)(row + j) * 512 + c] = (__bf16)v;
            }
        }
    }
}

// ---------------------------------------------------------------------------
// Batched GEMM: out[b,i,j] = 0.125 * sum_c Q[b,i,c] * K[b,j,c]
// Q,K: [8, 1024, 512] bf16; out: [8, 1024, 1024] f32
// grid: (8, 8, 8) = (colTile, rowTile, batch); block 256
// ---------------------------------------------------------------------------
__global__ __launch_bounds__(256, 2)
void attn_kernel(const __bf16* __restrict__ Q,
                 const __bf16* __restrict__ Kb,
                 float* __restrict__ out)
{
    __shared__ __bf16 As[128 * LDSW];
    __shared__ __bf16 Bs[128 * LDSW];

    const int tid  = threadIdx.x;
    const int lane = tid & 63;
    const int wid  = tid >> 6;
    const int wr   = wid >> 1;
    const int wc   = wid & 1;
    const int b    = blockIdx.z;
    const int brow = blockIdx.y * 128;
    const int bcol = blockIdx.x * 128;

    const __bf16* Qb = Q  + (size_t)b * 1024 * 512;
    const __bf16* Kp = Kb + (size_t)b * 1024 * 512;

    f32x4 acc[4][4] = {};

    const int srow = tid >> 1;
    const int soff = (tid & 1) * 32;
    const __bf16* aSrc = Qb + (size_t)(brow + srow) * 512 + soff;
    const __bf16* bSrc = Kp + (size_t)(bcol + srow) * 512 + soff;
    __bf16* aDst = &As[srow * LDSW + soff];
    __bf16* bDst = &Bs[srow * LDSW + soff];

    const int fr = lane & 15;
    const int fk = (lane >> 4) * 8;

    for (int k0 = 0; k0 < 512; k0 += BK) {
        __syncthreads();
        #pragma unroll
        for (int i = 0; i < 4; ++i)
            *(bf16x8*)(aDst + i * 8) = *(const bf16x8*)(aSrc + k0 + i * 8);
        #pragma unroll
        for (int i = 0; i < 4; ++i)
            *(bf16x8*)(bDst + i * 8) = *(const bf16x8*)(bSrc + k0 + i * 8);
        __syncthreads();

        #pragma unroll
        for (int kk = 0; kk < 2; ++kk) {
            bf16x8 af[4], bf[4];
            #pragma unroll
            for (int m = 0; m < 4; ++m)
                af[m] = *(const bf16x8*)(&As[(wr * 64 + m * 16 + fr) * LDSW + kk * 32 + fk]);
            #pragma unroll
            for (int n = 0; n < 4; ++n)
                bf[n] = *(const bf16x8*)(&Bs[(wc * 64 + n * 16 + fr) * LDSW + kk * 32 + fk]);
            #pragma unroll
            for (int m = 0; m < 4; ++m)
                #pragma unroll
                for (int n = 0; n < 4; ++n)
                    acc[m][n] = __builtin_amdgcn_mfma_f32_16x16x32_bf16(af[m], bf[n], acc[m][n], 0, 0, 0);
        }
    }

    float* op = out + (size_t)b * 1024 * 1024;
    const int r0 = (lane >> 4) * 4;
    #pragma unroll
    for (int n = 0; n < 4; ++n) {
        const int col = bcol + wc * 64 + n * 16 + fr;
        #pragma unroll
        for (int m = 0; m < 4; ++m) {
            const int row = brow + wr * 64 + m * 16 + r0;
            #pragma unroll
            for (int j = 0; j < 4; ++j)
                op[(size_t)(row + j) * 1024 + col] = 0.125f * acc[m][n][j];
        }
    }
}

extern "C" void kernel_launch(void* const* d_in, const int* in_sizes, int n_in,
                              void* d_out, int out_size, void* d_ws, size_t ws_size,
                              hipStream_t stream) {
    const float* rna  = (const float*)d_in[0];  // [8,1024,1280]
    const float* prot = (const float*)d_in[1];  // [8,1024,1344]
    const float* Wq   = (const float*)d_in[2];  // [512,1280]
    const float* bq   = (const float*)d_in[3];  // [512]
    const float* Wk   = (const float*)d_in[4];  // [512,1344]
    const float* bk   = (const float*)d_in[5];  // [512]
    const float* rb   = (const float*)d_in[6];  // [512] (flat idx == channel)

    __bf16* qws = (__bf16*)d_ws;                       // [8192, 512] bf16 = 8 MB
    __bf16* kws = qws + (size_t)8192 * 512;            // [8192, 512] bf16 = 8 MB

    dim3 blk(256);
    proj_kernel<1><<<dim3(4, 64), blk, 0, stream>>>(rna,  Wq, bq, rb,      qws, 1280);
    proj_kernel<0><<<dim3(4, 64), blk, 0, stream>>>(prot, Wk, bk, nullptr, kws, 1344);
    attn_kernel<<<dim3(8, 8, 8), blk, 0, stream>>>(qws, kws, (float*)d_out);
}

// Round 2
// 122.951 us; speedup vs baseline: 1.2509x; 1.2509x over previous
//
#include <hip/hip_runtime.h>
#include <hip/hip_bf16.h>

// CrossAttentionOutLayer: out[b,i,j] = (1/H) * sum_c Q'[b,i,c] * K[b,j,c]
//   Q' = SCALE*(rna@Wq.T + bq) + rel_bias   (c = h*DK+d == flat rel_bias idx)
//   K  = prot@Wk.T + bk
// B=8 N=1024 M=1024 DIM2=1280 KIN=1344 H=8 DK=64 HDK=512 SCALE=0.125

typedef __bf16 bf16x8 __attribute__((ext_vector_type(8)));
typedef float f32x4 __attribute__((ext_vector_type(4)));

constexpr int LDSW = 72;    // padded LDS row stride (bf16): 144B rows -> 2-way bank alias (free, m136)

__device__ inline bf16x8 cvt2(const f32x4 a, const f32x4 b) {
    bf16x8 r;
    r[0] = (__bf16)a[0]; r[1] = (__bf16)a[1]; r[2] = (__bf16)a[2]; r[3] = (__bf16)a[3];
    r[4] = (__bf16)b[0]; r[5] = (__bf16)b[1]; r[6] = (__bf16)b[2]; r[7] = (__bf16)b[3];
    return r;
}

// ---------------------------------------------------------------------------
// Fused Q+K projection. 1024 blocks: wg<512 -> Q proj (rna@Wq.T), else K proj.
// Tile 128 rows x 64 cols, BK=64, 4 waves (2x2) of 64x32 each.
// Reg double-buffer: next K-step's f32 loads issued before MFMA section.
// ---------------------------------------------------------------------------
__global__ __launch_bounds__(256, 2)
void proj_all(const float* __restrict__ rna,  const float* __restrict__ prot,
              const float* __restrict__ Wq,   const float* __restrict__ bq,
              const float* __restrict__ Wk,   const float* __restrict__ bk,
              const float* __restrict__ rb,
              __bf16* __restrict__ qout, __bf16* __restrict__ kout)
{
    __shared__ __bf16 As[128 * LDSW];   // 18 KB
    __shared__ __bf16 Ws[64 * LDSW];    // 9 KB

    // bijective XCD swizzle (nwg=1024 % 8 == 0): XCD x gets wg [x*128, x*128+128)
    const int bid = blockIdx.x;
    const int wg  = (bid & 7) * 128 + (bid >> 3);
    const bool isQ = wg < 512;
    const int lwg  = isQ ? wg : wg - 512;
    const int brow = (lwg >> 3) * 128;   // 64 row-tiles per matrix
    const int bcol = (lwg & 7) * 64;     // 8 col-tiles

    const float* A    = isQ ? rna : prot;
    const float* W    = isQ ? Wq  : Wk;
    const float* bias = isQ ? bq  : bk;
    __bf16*      out  = isQ ? qout : kout;
    const int    K    = isQ ? 1280 : 1344;

    const int tid  = threadIdx.x;
    const int lane = tid & 63;
    const int wid  = tid >> 6;
    const int wr   = wid >> 1;           // wave row (0..1) -> 64 rows each
    const int wc   = wid & 1;            // wave col (0..1) -> 32 cols each

    // staging: A 128x64 f32 -> 2 thr/row, 32 f32 each; W 64x64 -> 4 thr/row, 16 f32
    const int arow = tid >> 1, acol = (tid & 1) * 32;
    const int wrow = tid >> 2, wcol = (tid & 3) * 16;
    const float* aSrc = A + (size_t)(brow + arow) * K + acol;
    const float* wSrc = W + (size_t)(bcol + wrow) * K + wcol;
    __bf16* aDst = &As[arow * LDSW + acol];
    __bf16* wDst = &Ws[wrow * LDSW + wcol];

    const int fr = lane & 15;
    const int fk = (lane >> 4) * 8;

    f32x4 acc[4][2] = {};
    f32x4 ra[8], rw[4];

    #pragma unroll
    for (int i = 0; i < 8; ++i) ra[i] = *(const f32x4*)(aSrc + i * 4);
    #pragma unroll
    for (int i = 0; i < 4; ++i) rw[i] = *(const f32x4*)(wSrc + i * 4);

    for (int k0 = 0; k0 < K; k0 += 64) {
        __syncthreads();                       // prev iter's ds_reads done
        #pragma unroll
        for (int i = 0; i < 4; ++i)
            *(bf16x8*)(aDst + i * 8) = cvt2(ra[2 * i], ra[2 * i + 1]);
        *(bf16x8*)(wDst)     = cvt2(rw[0], rw[1]);
        *(bf16x8*)(wDst + 8) = cvt2(rw[2], rw[3]);
        __syncthreads();

        if (k0 + 64 < K) {                     // issue next tile early; lands under MFMA
            #pragma unroll
            for (int i = 0; i < 8; ++i) ra[i] = *(const f32x4*)(aSrc + k0 + 64 + i * 4);
            #pragma unroll
            for (int i = 0; i < 4; ++i) rw[i] = *(const f32x4*)(wSrc + k0 + 64 + i * 4);
        }

        #pragma unroll
        for (int kk = 0; kk < 2; ++kk) {
            bf16x8 af[4], bw[2];
            #pragma unroll
            for (int m = 0; m < 4; ++m)
                af[m] = *(const bf16x8*)(&As[(wr * 64 + m * 16 + fr) * LDSW + kk * 32 + fk]);
            #pragma unroll
            for (int n = 0; n < 2; ++n)
                bw[n] = *(const bf16x8*)(&Ws[(wc * 32 + n * 16 + fr) * LDSW + kk * 32 + fk]);
            #pragma unroll
            for (int m = 0; m < 4; ++m)
                #pragma unroll
                for (int n = 0; n < 2; ++n)
                    acc[m][n] = __builtin_amdgcn_mfma_f32_16x16x32_bf16(af[m], bw[n], acc[m][n], 0, 0, 0);
        }
    }

    // C/D layout: col = lane&15, row = (lane>>4)*4 + j  [m89-verified]
    const int r0 = (lane >> 4) * 4;
    #pragma unroll
    for (int n = 0; n < 2; ++n) {
        const int c = bcol + wc * 32 + n * 16 + fr;
        const float bv = bias[c];
        const float rv = isQ ? rb[c] : 0.0f;
        #pragma unroll
        for (int m = 0; m < 4; ++m) {
            const int row = brow + wr * 64 + m * 16 + r0;
            #pragma unroll
            for (int j = 0; j < 4; ++j) {
                float v = acc[m][n][j] + bv;
                if (isQ) v = 0.125f * v + rv;
                out[(size_t)(row + j) * 512 + c] = (__bf16)v;
            }
        }
    }
}

// ---------------------------------------------------------------------------
// Batched GEMM (m97 structure): out[b,i,j] = 0.125 * sum_c Q[b,i,c]*K[b,j,c]
// 128x128 tile, BK=64, global_load_lds width-16 staging, linear LDS.
// grid (8, 8, 8) = (colTile, rowTile, batch); 256 threads (4 waves 2x2 of 64x64)
// ---------------------------------------------------------------------------
__global__ __launch_bounds__(256, 2)
void attn_kernel(const __bf16* __restrict__ Q,
                 const __bf16* __restrict__ Kb,
                 float* __restrict__ out)
{
    __shared__ __bf16 As[128 * 64];   // 16 KB, linear (global_load_lds needs contiguous)
    __shared__ __bf16 Bs[128 * 64];

    const int tid  = threadIdx.x;
    const int lane = tid & 63;
    const int wid  = tid >> 6;
    const int wr   = wid >> 1;
    const int wc   = wid & 1;
    const int b    = blockIdx.z;
    const int brow = blockIdx.y * 128;
    const int bcol = blockIdx.x * 128;

    const __bf16* Qb = Q  + (size_t)b * 1024 * 512;
    const __bf16* Kp = Kb + (size_t)b * 1024 * 512;

    const int fr = lane & 15;
    const int fk = (lane >> 4) * 8;

    f32x4 acc[4][4] = {};

    // per gload_lds inst: 64 lanes x 16B = 1024B = 8 rows of 64 bf16.
    // lane l -> row base+(l>>3), col (l&7)*8 ; LDS dst wave-uniform.
    const int lrow = lane >> 3;
    const int lcol = (lane & 7) * 8;

    for (int k0 = 0; k0 < 512; k0 += 64) {
        __syncthreads();                       // prev iter's ds_reads done
        #pragma unroll
        for (int i = 0; i < 4; ++i) {
            const int rbase = wid * 32 + i * 8;
            const __bf16* sa = Qb + (size_t)(brow + rbase + lrow) * 512 + k0 + lcol;
            const __bf16* sb = Kp + (size_t)(bcol + rbase + lrow) * 512 + k0 + lcol;
            __builtin_amdgcn_global_load_lds(
                (const __attribute__((address_space(1))) void*)sa,
                (__attribute__((address_space(3))) void*)&As[rbase * 64], 16, 0, 0);
            __builtin_amdgcn_global_load_lds(
                (const __attribute__((address_space(1))) void*)sb,
                (__attribute__((address_space(3))) void*)&Bs[rbase * 64], 16, 0, 0);
        }
        __syncthreads();                       // drains vmcnt -> tiles resident

        #pragma unroll
        for (int kk = 0; kk < 2; ++kk) {
            bf16x8 af[4], bf_[4];
            #pragma unroll
            for (int m = 0; m < 4; ++m)
                af[m] = *(const bf16x8*)(&As[(wr * 64 + m * 16 + fr) * 64 + kk * 32 + fk]);
            #pragma unroll
            for (int n = 0; n < 4; ++n)
                bf_[n] = *(const bf16x8*)(&Bs[(wc * 64 + n * 16 + fr) * 64 + kk * 32 + fk]);
            #pragma unroll
            for (int m = 0; m < 4; ++m)
                #pragma unroll
                for (int n = 0; n < 4; ++n)
                    acc[m][n] = __builtin_amdgcn_mfma_f32_16x16x32_bf16(af[m], bf_[n], acc[m][n], 0, 0, 0);
        }
    }

    float* op = out + (size_t)b * 1024 * 1024;
    const int r0 = (lane >> 4) * 4;
    #pragma unroll
    for (int n = 0; n < 4; ++n) {
        const int col = bcol + wc * 64 + n * 16 + fr;
        #pragma unroll
        for (int m = 0; m < 4; ++m) {
            const int row = brow + wr * 64 + m * 16 + r0;
            #pragma unroll
            for (int j = 0; j < 4; ++j)
                op[(size_t)(row + j) * 1024 + col] = 0.125f * acc[m][n][j];
        }
    }
}

extern "C" void kernel_launch(void* const* d_in, const int* in_sizes, int n_in,
                              void* d_out, int out_size, void* d_ws, size_t ws_size,
                              hipStream_t stream) {
    const float* rna  = (const float*)d_in[0];  // [8,1024,1280]
    const float* prot = (const float*)d_in[1];  // [8,1024,1344]
    const float* Wq   = (const float*)d_in[2];  // [512,1280]
    const float* bq   = (const float*)d_in[3];  // [512]
    const float* Wk   = (const float*)d_in[4];  // [512,1344]
    const float* bk   = (const float*)d_in[5];  // [512]
    const float* rb   = (const float*)d_in[6];  // [512] (flat idx == channel)

    __bf16* qws = (__bf16*)d_ws;                // [8192, 512] bf16 = 8 MB
    __bf16* kws = qws + (size_t)8192 * 512;     // [8192, 512] bf16 = 8 MB

    proj_all<<<dim3(1024), dim3(256), 0, stream>>>(rna, prot, Wq, bq, Wk, bk, rb, qws, kws);
    attn_kernel<<<dim3(8, 8, 8), dim3(256), 0, stream>>>(qws, kws, (float*)d_out);
}

// Round 3
// 112.837 us; speedup vs baseline: 1.3631x; 1.0896x over previous
//
#include <hip/hip_runtime.h>
#include <hip/hip_bf16.h>

// CrossAttentionOutLayer: out[b,i,j] = (1/H) * sum_c Q'[b,i,c] * K[b,j,c]
//   Q' = SCALE*(rna@Wq.T + bq) + rel_bias   (c = h*DK+d == flat rel_bias idx)
//   K  = prot@Wk.T + bk
// B=8 N=1024 M=1024 DIM2=1280 KIN=1344 H=8 DK=64 HDK=512 SCALE=0.125

typedef __bf16 bf16x8 __attribute__((ext_vector_type(8)));
typedef float f32x4 __attribute__((ext_vector_type(4)));

__device__ inline bf16x8 cvt2(const f32x4 a, const f32x4 b) {
    bf16x8 r;
    r[0] = (__bf16)a[0]; r[1] = (__bf16)a[1]; r[2] = (__bf16)a[2]; r[3] = (__bf16)a[3];
    r[4] = (__bf16)b[0]; r[5] = (__bf16)b[1]; r[6] = (__bf16)b[2]; r[7] = (__bf16)b[3];
    return r;
}

// ---------------------------------------------------------------------------
// Fused Q+K projection, m97 structure with f32 operands in LDS.
// Tile 128 rows x 128 cols, BK=64. 4 waves (2x2), each 64x64 output.
// Staging: global_load_lds width-16 (async, no VGPR roundtrip -> compiler
// cannot sink it; the R2 reg-prefetch was sunk, exposing latency each iter).
// Fragments: read f32 pairs from LDS, cvt to bf16x8 in-reg, MFMA 16x16x32.
// grid 512 = 2 blocks/CU; bijective XCD swizzle (512%8==0).
// ---------------------------------------------------------------------------
__global__ __launch_bounds__(256, 2)
void proj_all(const float* __restrict__ rna,  const float* __restrict__ prot,
              const float* __restrict__ Wq,   const float* __restrict__ bq,
              const float* __restrict__ Wk,   const float* __restrict__ bk,
              const float* __restrict__ rb,
              __bf16* __restrict__ qout, __bf16* __restrict__ kout)
{
    __shared__ float As[128 * 64];   // 32 KB, linear (global_load_lds constraint)
    __shared__ float Ws[128 * 64];   // 32 KB

    const int bid = blockIdx.x;
    const int wg  = (bid & 7) * 64 + (bid >> 3);   // XCD-contiguous chunks
    const bool isQ = wg < 256;
    const int lwg  = isQ ? wg : wg - 256;
    const int brow = (lwg >> 2) * 128;   // 64 row-tiles per matrix
    const int bcol = (lwg & 3) * 128;    // 4 col-tiles (N=512)

    const float* A    = isQ ? rna : prot;
    const float* W    = isQ ? Wq  : Wk;
    const float* bias = isQ ? bq  : bk;
    __bf16*      out  = isQ ? qout : kout;
    const int    K    = isQ ? 1280 : 1344;

    const int tid  = threadIdx.x;
    const int lane = tid & 63;
    const int wid  = tid >> 6;
    const int wr   = wid >> 1;
    const int wc   = wid & 1;
    const int fr   = lane & 15;
    const int fk   = (lane >> 4) * 8;

    // one gload_lds inst: 64 lanes x 16B = 1KB = 4 rows of 64 f32.
    // lane l -> row +(l>>4), f32 col (l&15)*4 ; LDS dst wave-uniform + lane*16B.
    const int lrow = lane >> 4;
    const int lcol = (lane & 15) * 4;
    const float* aBase = A + (size_t)(brow + wid * 32 + lrow) * K + lcol;
    const float* wBase = W + (size_t)(bcol + wid * 32 + lrow) * K + lcol;

    f32x4 acc[4][4] = {};

    for (int k0 = 0; k0 < K; k0 += 64) {
        __syncthreads();                       // prev iter's frag reads done
        #pragma unroll
        for (int i = 0; i < 8; ++i) {
            __builtin_amdgcn_global_load_lds(
                (const __attribute__((address_space(1))) void*)(aBase + (size_t)(i * 4) * K + k0),
                (__attribute__((address_space(3))) void*)&As[(wid * 32 + i * 4) * 64], 16, 0, 0);
            __builtin_amdgcn_global_load_lds(
                (const __attribute__((address_space(1))) void*)(wBase + (size_t)(i * 4) * K + k0),
                (__attribute__((address_space(3))) void*)&Ws[(wid * 32 + i * 4) * 64], 16, 0, 0);
        }
        __syncthreads();                       // drains vmcnt -> tiles resident

        #pragma unroll
        for (int kk = 0; kk < 2; ++kk) {
            bf16x8 af[4], bw[4];
            #pragma unroll
            for (int m = 0; m < 4; ++m) {
                const float* p = &As[(wr * 64 + m * 16 + fr) * 64 + kk * 32 + fk];
                af[m] = cvt2(*(const f32x4*)p, *(const f32x4*)(p + 4));
            }
            #pragma unroll
            for (int n = 0; n < 4; ++n) {
                const float* p = &Ws[(wc * 64 + n * 16 + fr) * 64 + kk * 32 + fk];
                bw[n] = cvt2(*(const f32x4*)p, *(const f32x4*)(p + 4));
            }
            #pragma unroll
            for (int m = 0; m < 4; ++m)
                #pragma unroll
                for (int n = 0; n < 4; ++n)
                    acc[m][n] = __builtin_amdgcn_mfma_f32_16x16x32_bf16(af[m], bw[n], acc[m][n], 0, 0, 0);
        }
    }

    // C/D layout: col = lane&15, row = (lane>>4)*4 + j  [m89-verified]
    const int r0 = (lane >> 4) * 4;
    #pragma unroll
    for (int n = 0; n < 4; ++n) {
        const int c = bcol + wc * 64 + n * 16 + fr;
        const float bv = bias[c];
        const float rv = isQ ? rb[c] : 0.0f;
        #pragma unroll
        for (int m = 0; m < 4; ++m) {
            const int row = brow + wr * 64 + m * 16 + r0;
            #pragma unroll
            for (int j = 0; j < 4; ++j) {
                float v = acc[m][n][j] + bv;
                if (isQ) v = 0.125f * v + rv;
                out[(size_t)(row + j) * 512 + c] = (__bf16)v;
            }
        }
    }
}

// ---------------------------------------------------------------------------
// Batched GEMM (m97 structure): out[b,i,j] = 0.125 * sum_c Q[b,i,c]*K[b,j,c]
// 128x128 tile, BK=64, global_load_lds width-16 staging, linear LDS.
// grid (8, 8, 8); 256 threads (4 waves 2x2 of 64x64)
// ---------------------------------------------------------------------------
__global__ __launch_bounds__(256, 2)
void attn_kernel(const __bf16* __restrict__ Q,
                 const __bf16* __restrict__ Kb,
                 float* __restrict__ out)
{
    __shared__ __bf16 As[128 * 64];   // 16 KB, linear
    __shared__ __bf16 Bs[128 * 64];

    const int tid  = threadIdx.x;
    const int lane = tid & 63;
    const int wid  = tid >> 6;
    const int wr   = wid >> 1;
    const int wc   = wid & 1;
    const int b    = blockIdx.z;
    const int brow = blockIdx.y * 128;
    const int bcol = blockIdx.x * 128;

    const __bf16* Qb = Q  + (size_t)b * 1024 * 512;
    const __bf16* Kp = Kb + (size_t)b * 1024 * 512;

    const int fr = lane & 15;
    const int fk = (lane >> 4) * 8;

    f32x4 acc[4][4] = {};

    // per inst: 64 lanes x 16B = 1KB = 8 rows of 64 bf16.
    const int lrow = lane >> 3;
    const int lcol = (lane & 7) * 8;

    for (int k0 = 0; k0 < 512; k0 += 64) {
        __syncthreads();
        #pragma unroll
        for (int i = 0; i < 4; ++i) {
            const int rbase = wid * 32 + i * 8;
            const __bf16* sa = Qb + (size_t)(brow + rbase + lrow) * 512 + k0 + lcol;
            const __bf16* sb = Kp + (size_t)(bcol + rbase + lrow) * 512 + k0 + lcol;
            __builtin_amdgcn_global_load_lds(
                (const __attribute__((address_space(1))) void*)sa,
                (__attribute__((address_space(3))) void*)&As[rbase * 64], 16, 0, 0);
            __builtin_amdgcn_global_load_lds(
                (const __attribute__((address_space(1))) void*)sb,
                (__attribute__((address_space(3))) void*)&Bs[rbase * 64], 16, 0, 0);
        }
        __syncthreads();

        #pragma unroll
        for (int kk = 0; kk < 2; ++kk) {
            bf16x8 af[4], bf_[4];
            #pragma unroll
            for (int m = 0; m < 4; ++m)
                af[m] = *(const bf16x8*)(&As[(wr * 64 + m * 16 + fr) * 64 + kk * 32 + fk]);
            #pragma unroll
            for (int n = 0; n < 4; ++n)
                bf_[n] = *(const bf16x8*)(&Bs[(wc * 64 + n * 16 + fr) * 64 + kk * 32 + fk]);
            #pragma unroll
            for (int m = 0; m < 4; ++m)
                #pragma unroll
                for (int n = 0; n < 4; ++n)
                    acc[m][n] = __builtin_amdgcn_mfma_f32_16x16x32_bf16(af[m], bf_[n], acc[m][n], 0, 0, 0);
        }
    }

    float* op = out + (size_t)b * 1024 * 1024;
    const int r0 = (lane >> 4) * 4;
    #pragma unroll
    for (int n = 0; n < 4; ++n) {
        const int col = bcol + wc * 64 + n * 16 + fr;
        #pragma unroll
        for (int m = 0; m < 4; ++m) {
            const int row = brow + wr * 64 + m * 16 + r0;
            #pragma unroll
            for (int j = 0; j < 4; ++j)
                op[(size_t)(row + j) * 1024 + col] = 0.125f * acc[m][n][j];
        }
    }
}

extern "C" void kernel_launch(void* const* d_in, const int* in_sizes, int n_in,
                              void* d_out, int out_size, void* d_ws, size_t ws_size,
                              hipStream_t stream) {
    const float* rna  = (const float*)d_in[0];  // [8,1024,1280]
    const float* prot = (const float*)d_in[1];  // [8,1024,1344]
    const float* Wq   = (const float*)d_in[2];  // [512,1280]
    const float* bq   = (const float*)d_in[3];  // [512]
    const float* Wk   = (const float*)d_in[4];  // [512,1344]
    const float* bk   = (const float*)d_in[5];  // [512]
    const float* rb   = (const float*)d_in[6];  // [512] (flat idx == channel)

    __bf16* qws = (__bf16*)d_ws;                // [8192, 512] bf16 = 8 MB
    __bf16* kws = qws + (size_t)8192 * 512;     // [8192, 512] bf16 = 8 MB

    proj_all<<<dim3(512), dim3(256), 0, stream>>>(rna, prot, Wq, bq, Wk, bk, rb, qws, kws);
    attn_kernel<<<dim3(8, 8, 8), dim3(256), 0, stream>>>(qws, kws, (float*)d_out);
}

// Round 4
// 61.711 us; speedup vs baseline: 2.4923x; 1.8285x over previous
//
#include <hip/hip_runtime.h>
#include <hip/hip_bf16.h>

// CrossAttentionOutLayer: out[b,i,j] = (1/H) * sum_c Q'[b,i,c] * K[b,j,c]
//   Q' = SCALE*(rna@Wq.T + bq) + rel_bias   (c = h*DK+d == flat rel_bias idx)
//   K  = prot@Wk.T + bk
// B=8 N=1024 M=1024 DIM2=1280 KIN=1344 H=8 DK=64 HDK=512 SCALE=0.125
//
// LDS bank-conflict fix (R3 post-mortem: SQ_LDS_BANK_CONFLICT=3.76e7):
// both-sides XOR swizzle (rule #21): global_load_lds dest stays LINEAR;
// per-lane GLOBAL source column is pre-permuted by mask3(row) on the 16B
// chunk index; ds_read applies the same XOR. mask3(r)=((r&3)<<1)|((r>>2)&1)
// spreads each quarter-wave's 16 lanes over all 8 four-bank groups.

typedef __bf16 bf16x8 __attribute__((ext_vector_type(8)));
typedef float f32x4 __attribute__((ext_vector_type(4)));

__device__ inline bf16x8 cvt2(const f32x4 a, const f32x4 b) {
    bf16x8 r;
    r[0] = (__bf16)a[0]; r[1] = (__bf16)a[1]; r[2] = (__bf16)a[2]; r[3] = (__bf16)a[3];
    r[4] = (__bf16)b[0]; r[5] = (__bf16)b[1]; r[6] = (__bf16)b[2]; r[7] = (__bf16)b[3];
    return r;
}

// ---------------------------------------------------------------------------
// Fused Q+K projection, m97 structure, f32 operands in LDS (swizzled).
// Tile 128x128, BK=64, 4 waves (2x2) of 64x64. grid 512, XCD swizzle.
// ---------------------------------------------------------------------------
__global__ __launch_bounds__(256, 2)
void proj_all(const float* __restrict__ rna,  const float* __restrict__ prot,
              const float* __restrict__ Wq,   const float* __restrict__ bq,
              const float* __restrict__ Wk,   const float* __restrict__ bk,
              const float* __restrict__ rb,
              __bf16* __restrict__ qout, __bf16* __restrict__ kout)
{
    __shared__ float As[128 * 64];   // 32 KB, linear dest (swizzled content)
    __shared__ float Ws[128 * 64];   // 32 KB

    const int bid = blockIdx.x;
    const int wg  = (bid & 7) * 64 + (bid >> 3);   // bijective XCD swizzle (512%8==0)
    const bool isQ = wg < 256;
    const int lwg  = isQ ? wg : wg - 256;
    const int brow = (lwg >> 2) * 128;
    const int bcol = (lwg & 3) * 128;

    const float* A    = isQ ? rna : prot;
    const float* W    = isQ ? Wq  : Wk;
    const float* bias = isQ ? bq  : bk;
    __bf16*      out  = isQ ? qout : kout;
    const int    K    = isQ ? 1280 : 1344;

    const int tid  = threadIdx.x;
    const int lane = tid & 63;
    const int wid  = tid >> 6;
    const int wr   = wid >> 1;
    const int wc   = wid & 1;
    const int fr   = lane & 15;
    const int q4   = lane >> 4;          // quarter-wave id

    // ---- staging addresses (f32 tile: 16 chunks of 16B per 256B row) ----
    // one gload_lds: 1KB = 4 rows x 16 chunks; lane l -> row +(l>>4), chunk l&15.
    // swizzle: LDS chunk (r,ci) must hold global chunk ci^mask3(r).
    // row&7 = (i&1)*4 + (l>>4)  =>  mask3 = ((l>>4)<<1) | (i&1).
    const int lrow = lane >> 4;
    const int ciE  = (lane & 15) ^ (lrow << 1);        // i even
    const int ciO  = ciE ^ 1;                          // i odd
    const float* aBaseE = A + (size_t)(brow + wid * 32 + lrow) * K + ciE * 4;
    const float* aBaseO = A + (size_t)(brow + wid * 32 + lrow) * K + ciO * 4;
    const float* wBaseE = W + (size_t)(bcol + wid * 32 + lrow) * K + ciE * 4;
    const float* wBaseO = W + (size_t)(bcol + wid * 32 + lrow) * K + ciO * 4;

    // ---- fragment-read swizzle: R&3 = fr&3, (R>>2)&1 = (fr>>2)&1 ----
    const int rmask = ((fr & 3) << 1) | ((fr >> 2) & 1);

    f32x4 acc[4][4] = {};

    for (int k0 = 0; k0 < K; k0 += 64) {
        __syncthreads();                       // prev iter's frag reads done
        #pragma unroll
        for (int i = 0; i < 8; ++i) {
            const float* sa = ((i & 1) ? aBaseO : aBaseE) + (size_t)(i * 4) * K + k0;
            const float* sw = ((i & 1) ? wBaseO : wBaseE) + (size_t)(i * 4) * K + k0;
            __builtin_amdgcn_global_load_lds(
                (const __attribute__((address_space(1))) void*)sa,
                (__attribute__((address_space(3))) void*)&As[(wid * 32 + i * 4) * 64], 16, 0, 0);
            __builtin_amdgcn_global_load_lds(
                (const __attribute__((address_space(1))) void*)sw,
                (__attribute__((address_space(3))) void*)&Ws[(wid * 32 + i * 4) * 64], 16, 0, 0);
        }
        __syncthreads();                       // tiles resident

        #pragma unroll
        for (int kk = 0; kk < 2; ++kk) {
            const int c0 = kk * 8 + 2 * q4;    // global chunk pair c0, c0+1
            bf16x8 af[4], bw[4];
            #pragma unroll
            for (int m = 0; m < 4; ++m) {
                const float* rowp = &As[(wr * 64 + m * 16 + fr) * 64];
                f32x4 v0 = *(const f32x4*)(rowp + (((c0    ) ^ rmask) << 2));
                f32x4 v1 = *(const f32x4*)(rowp + (((c0 + 1) ^ rmask) << 2));
                af[m] = cvt2(v0, v1);
            }
            #pragma unroll
            for (int n = 0; n < 4; ++n) {
                const float* rowp = &Ws[(wc * 64 + n * 16 + fr) * 64];
                f32x4 v0 = *(const f32x4*)(rowp + (((c0    ) ^ rmask) << 2));
                f32x4 v1 = *(const f32x4*)(rowp + (((c0 + 1) ^ rmask) << 2));
                bw[n] = cvt2(v0, v1);
            }
            #pragma unroll
            for (int m = 0; m < 4; ++m)
                #pragma unroll
                for (int n = 0; n < 4; ++n)
                    acc[m][n] = __builtin_amdgcn_mfma_f32_16x16x32_bf16(af[m], bw[n], acc[m][n], 0, 0, 0);
        }
    }

    // C/D layout: col = lane&15, row = (lane>>4)*4 + j  [m89-verified]
    const int r0 = (lane >> 4) * 4;
    #pragma unroll
    for (int n = 0; n < 4; ++n) {
        const int c = bcol + wc * 64 + n * 16 + fr;
        const float bv = bias[c];
        const float rv = isQ ? rb[c] : 0.0f;
        #pragma unroll
        for (int m = 0; m < 4; ++m) {
            const int row = brow + wr * 64 + m * 16 + r0;
            #pragma unroll
            for (int j = 0; j < 4; ++j) {
                float v = acc[m][n][j] + bv;
                if (isQ) v = 0.125f * v + rv;
                out[(size_t)(row + j) * 512 + c] = (__bf16)v;
            }
        }
    }
}

// ---------------------------------------------------------------------------
// Batched GEMM: out[b,i,j] = 0.125 * sum_c Q[b,i,c]*K[b,j,c]
// 128x128 tile, BK=64, gload_lds staging, swizzled bf16 LDS.
// ---------------------------------------------------------------------------
__global__ __launch_bounds__(256, 2)
void attn_kernel(const __bf16* __restrict__ Q,
                 const __bf16* __restrict__ Kb,
                 float* __restrict__ out)
{
    __shared__ __bf16 As[128 * 64];   // 16 KB, linear dest (swizzled content)
    __shared__ __bf16 Bs[128 * 64];

    const int tid  = threadIdx.x;
    const int lane = tid & 63;
    const int wid  = tid >> 6;
    const int wr   = wid >> 1;
    const int wc   = wid & 1;
    const int b    = blockIdx.z;
    const int brow = blockIdx.y * 128;
    const int bcol = blockIdx.x * 128;

    const __bf16* Qb = Q  + (size_t)b * 1024 * 512;
    const __bf16* Kp = Kb + (size_t)b * 1024 * 512;

    const int fr = lane & 15;
    const int q4 = lane >> 4;

    f32x4 acc[4][4] = {};

    // one gload_lds: 1KB = 8 rows x 8 chunks (bf16: 8 elems/chunk).
    // lane l -> row +(l>>3), chunk l&7; row&7 = l>>3 for all i (rbase%8==0).
    const int lr3 = lane >> 3;
    const int m3  = ((lr3 & 3) << 1) | ((lr3 >> 2) & 1);
    const int scol = ((lane & 7) ^ m3) * 8;            // swizzled global bf16 col
    const int rmask = ((fr & 3) << 1) | ((fr >> 2) & 1);

    for (int k0 = 0; k0 < 512; k0 += 64) {
        __syncthreads();
        #pragma unroll
        for (int i = 0; i < 4; ++i) {
            const int rbase = wid * 32 + i * 8;
            const __bf16* sa = Qb + (size_t)(brow + rbase + lr3) * 512 + k0 + scol;
            const __bf16* sb = Kp + (size_t)(bcol + rbase + lr3) * 512 + k0 + scol;
            __builtin_amdgcn_global_load_lds(
                (const __attribute__((address_space(1))) void*)sa,
                (__attribute__((address_space(3))) void*)&As[rbase * 64], 16, 0, 0);
            __builtin_amdgcn_global_load_lds(
                (const __attribute__((address_space(1))) void*)sb,
                (__attribute__((address_space(3))) void*)&Bs[rbase * 64], 16, 0, 0);
        }
        __syncthreads();

        #pragma unroll
        for (int kk = 0; kk < 2; ++kk) {
            const int ci = kk * 4 + q4;                // global chunk
            bf16x8 af[4], bf_[4];
            #pragma unroll
            for (int m = 0; m < 4; ++m)
                af[m] = *(const bf16x8*)(&As[(wr * 64 + m * 16 + fr) * 64 + ((ci ^ rmask) << 3)]);
            #pragma unroll
            for (int n = 0; n < 4; ++n)
                bf_[n] = *(const bf16x8*)(&Bs[(wc * 64 + n * 16 + fr) * 64 + ((ci ^ rmask) << 3)]);
            #pragma unroll
            for (int m = 0; m < 4; ++m)
                #pragma unroll
                for (int n = 0; n < 4; ++n)
                    acc[m][n] = __builtin_amdgcn_mfma_f32_16x16x32_bf16(af[m], bf_[n], acc[m][n], 0, 0, 0);
        }
    }

    float* op = out + (size_t)b * 1024 * 1024;
    const int r0 = (lane >> 4) * 4;
    #pragma unroll
    for (int n = 0; n < 4; ++n) {
        const int col = bcol + wc * 64 + n * 16 + fr;
        #pragma unroll
        for (int m = 0; m < 4; ++m) {
            const int row = brow + wr * 64 + m * 16 + r0;
            #pragma unroll
            for (int j = 0; j < 4; ++j)
                op[(size_t)(row + j) * 1024 + col] = 0.125f * acc[m][n][j];
        }
    }
}

extern "C" void kernel_launch(void* const* d_in, const int* in_sizes, int n_in,
                              void* d_out, int out_size, void* d_ws, size_t ws_size,
                              hipStream_t stream) {
    const float* rna  = (const float*)d_in[0];  // [8,1024,1280]
    const float* prot = (const float*)d_in[1];  // [8,1024,1344]
    const float* Wq   = (const float*)d_in[2];  // [512,1280]
    const float* bq   = (const float*)d_in[3];  // [512]
    const float* Wk   = (const float*)d_in[4];  // [512,1344]
    const float* bk   = (const float*)d_in[5];  // [512]
    const float* rb   = (const float*)d_in[6];  // [512] (flat idx == channel)

    __bf16* qws = (__bf16*)d_ws;                // [8192, 512] bf16 = 8 MB
    __bf16* kws = qws + (size_t)8192 * 512;     // [8192, 512] bf16 = 8 MB

    proj_all<<<dim3(512), dim3(256), 0, stream>>>(rna, prot, Wq, bq, Wk, bk, rb, qws, kws);
    attn_kernel<<<dim3(8, 8, 8), dim3(256), 0, stream>>>(qws, kws, (float*)d_out);
}